// Round 3
// baseline (181.264 us; speedup 1.0000x reference)
//
#include <hip/hip_runtime.h>
#include <math.h>

// B=4, T=2048, N_EMBD=1024, HEAD=64. Scores scaled by *sqrt(64)=8 (faithful).
#define NE 1024
#define HS 64
#define TT 2048

typedef __bf16    v8bf __attribute__((ext_vector_type(8)));
typedef _Float16  v8h  __attribute__((ext_vector_type(8)));
typedef float     v4f  __attribute__((ext_vector_type(4)));

#define MFMA_BF(a, b, c) __builtin_amdgcn_mfma_f32_16x16x32_bf16((a), (b), (c), 0, 0, 0)
#define MFMA_F16(a, b, c) __builtin_amdgcn_mfma_f32_16x16x32_f16((a), (b), (c), 0, 0, 0)

// ---------------------------------------------------------------------------
// Prep: split Wq|Wk|Wv into transposed hi/lo bf16 wt[n][k] (n=0..191) via LDS
// transpose so both the W read and the wt writes are fully coalesced.
// Grid: (16 k-tiles, 3 n-tiles), 256 threads.
// ---------------------------------------------------------------------------
__global__ __launch_bounds__(256) void prep_w(
    const float* __restrict__ Wq, const float* __restrict__ Wk,
    const float* __restrict__ Wv, __bf16* __restrict__ wth, __bf16* __restrict__ wtl)
{
    __shared__ float t[64][65];
    const int k0 = blockIdx.x * 64, n0 = blockIdx.y * 64;
    const float* W = (n0 == 0) ? Wq : ((n0 == 64) ? Wk : Wv);
    const int tid = threadIdx.x;
    const int c = tid & 63, r4 = tid >> 6;
    #pragma unroll
    for (int p = 0; p < 16; ++p) {
        const int k = p * 4 + r4;
        t[k][c] = W[(size_t)(k0 + k) * HS + c];     // coalesced read
    }
    __syncthreads();
    #pragma unroll
    for (int p = 0; p < 16; ++p) {
        const int n = p * 4 + r4;
        const float w = t[c][n];                     // stride-65: conflict-free
        const __bf16 h = (__bf16)w;
        const size_t o = (size_t)(n0 + n) * NE + k0 + c;
        wth[o] = h;                                  // coalesced write
        wtl[o] = (__bf16)(w - (float)h);
    }
}

// ---------------------------------------------------------------------------
// Projection GEMM, split-precision bf16 MFMA, NO LDS.
// Block = 16 rows x 192 cols, 4 waves; wave w owns n-tiles 3w..3w+2.
// A fragments (x rows, hi/lo-converted in registers) are identical across the
// block's 4 waves -> L1 broadcast. B fragments straight from global (wt is
// 768 KB, L2-resident). Grid = 512 blocks -> 2 blocks/CU, 8 waves/CU, no
// barriers, no bank conflicts.
// Epilogue: q (x8, hi/lo bf16), k (hi/lo bf16), v transposed fp16.
// ---------------------------------------------------------------------------
__global__ __launch_bounds__(256, 2) void proj(
    const float* __restrict__ x, const __bf16* __restrict__ wth,
    const __bf16* __restrict__ wtl,
    const float* __restrict__ bq, const float* __restrict__ bk,
    const float* __restrict__ bv,
    __bf16* __restrict__ qh, __bf16* __restrict__ ql,
    __bf16* __restrict__ kh, __bf16* __restrict__ kl,
    _Float16* __restrict__ vt)
{
    const int m0 = blockIdx.x * 16;
    const int tid = threadIdx.x, lane = tid & 63, w = tid >> 6;
    const int quad = lane >> 4, l16 = lane & 15;

    v4f acc[3];
    #pragma unroll
    for (int i = 0; i < 3; ++i) acc[i] = (v4f){0.f, 0.f, 0.f, 0.f};

    const float* ap = x + (size_t)(m0 + l16) * NE + quad * 8;
    const size_t brow = (size_t)(w * 48 + l16) * NE + quad * 8;

    #pragma unroll 2
    for (int k0 = 0; k0 < NE; k0 += 32) {
        // A fragment: 8 fp32 -> hi/lo bf16 in registers
        const float4 f0 = *(const float4*)(ap + k0);
        const float4 f1 = *(const float4*)(ap + k0 + 4);
        const float vals[8] = {f0.x, f0.y, f0.z, f0.w, f1.x, f1.y, f1.z, f1.w};
        v8bf ah, al;
        #pragma unroll
        for (int i = 0; i < 8; ++i) {
            const __bf16 h = (__bf16)vals[i];
            ah[i] = h;
            al[i] = (__bf16)(vals[i] - (float)h);
        }
        #pragma unroll
        for (int j = 0; j < 3; ++j) {
            const size_t bo = brow + (size_t)j * 16 * NE + k0;
            const v8bf bh = *(const v8bf*)(wth + bo);
            const v8bf bl = *(const v8bf*)(wtl + bo);
            acc[j] = MFMA_BF(ah, bh, acc[j]);
            acc[j] = MFMA_BF(ah, bl, acc[j]);
            acc[j] = MFMA_BF(al, bh, acc[j]);
        }
    }

    // epilogue: C layout col=l16 (within n-tile), row=quad*4+reg
    #pragma unroll
    for (int j = 0; j < 3; ++j) {
        const int n = w * 48 + j * 16 + l16;
        const float bias = (n < 64) ? bq[n] : ((n < 128) ? bk[n - 64] : bv[n - 128]);
        #pragma unroll
        for (int reg = 0; reg < 4; ++reg) {
            const int row = m0 + quad * 4 + reg;
            const float v = acc[j][reg] + bias;
            if (n < 64) {
                const float s = v * 8.0f;            // fold score scale into q
                const __bf16 h = (__bf16)s;
                qh[(size_t)row * HS + n] = h;
                ql[(size_t)row * HS + n] = (__bf16)(s - (float)h);
            } else if (n < 128) {
                const __bf16 h = (__bf16)v;
                kh[(size_t)row * HS + n - 64] = h;
                kl[(size_t)row * HS + n - 64] = (__bf16)(v - (float)h);
            } else {
                const int b = row >> 11, tt = row & 2047, hc = n - 128;
                vt[((size_t)(b * HS + hc)) * TT + tt] = (_Float16)v;
            }
        }
    }
}

// ---------------------------------------------------------------------------
// Flash attention, MFMA. Block = 16 q-rows, 8 waves split the key range
// (round-robin 64-key tiles), independent online softmax, merged at the end.
// Fragments straight from global (L2-resident). P via wave-private LDS, fp16.
// 512 blocks x 8 waves -> 16 waves/CU.
// ---------------------------------------------------------------------------
__global__ __launch_bounds__(512, 4) void attn(
    const __bf16* __restrict__ qh, const __bf16* __restrict__ ql,
    const __bf16* __restrict__ kh, const __bf16* __restrict__ kl,
    const _Float16* __restrict__ vt, float* __restrict__ out)
{
    __shared__ __align__(16) _Float16 ps[8][16 * 72];  // wave-private P
    __shared__ float os[8][16 * 68];                   // merged O staging
    __shared__ float sm[8][16], sl[8][16];

    const int tid = threadIdx.x, lane = tid & 63, w = tid >> 6;
    const int quad = lane >> 4, l16 = lane & 15;
    const int b = blockIdx.x & 3, qi = blockIdx.x >> 2;
    const int q0 = (127 - qi) * 16;                    // heavy tiles first

    const size_t qrow = ((size_t)b * TT + q0 + l16) * HS;
    const v8bf Qh0 = *(const v8bf*)(qh + qrow + quad * 8);
    const v8bf Qh1 = *(const v8bf*)(qh + qrow + 32 + quad * 8);
    const v8bf Ql0 = *(const v8bf*)(ql + qrow + quad * 8);
    const v8bf Ql1 = *(const v8bf*)(ql + qrow + 32 + quad * 8);

    float mrow[4] = {-3e38f, -3e38f, -3e38f, -3e38f};
    float lrow[4] = {0.f, 0.f, 0.f, 0.f};
    v4f o[4];
    #pragma unroll
    for (int i = 0; i < 4; ++i) o[i] = (v4f){0.f, 0.f, 0.f, 0.f};

    const int irow = q0 + quad * 4;                    // + reg
    const int ntk = (q0 + 16 + 63) >> 6;

    for (int t = w; t < ntk; t += 8) {
        const int j0 = t * 64;
        v4f s[4];
        #pragma unroll
        for (int i = 0; i < 4; ++i) s[i] = (v4f){0.f, 0.f, 0.f, 0.f};

        #pragma unroll
        for (int nt = 0; nt < 4; ++nt) {
            const size_t krow = ((size_t)b * TT + j0 + nt * 16 + l16) * HS;
            v8bf Bh0 = *(const v8bf*)(kh + krow + quad * 8);
            v8bf Bh1 = *(const v8bf*)(kh + krow + 32 + quad * 8);
            v8bf Bl0 = *(const v8bf*)(kl + krow + quad * 8);
            v8bf Bl1 = *(const v8bf*)(kl + krow + 32 + quad * 8);
            s[nt] = MFMA_BF(Qh0, Bh0, s[nt]);
            s[nt] = MFMA_BF(Qh1, Bh1, s[nt]);
            s[nt] = MFMA_BF(Qh0, Bl0, s[nt]);
            s[nt] = MFMA_BF(Qh1, Bl1, s[nt]);
            s[nt] = MFMA_BF(Ql0, Bh0, s[nt]);
            s[nt] = MFMA_BF(Ql1, Bh1, s[nt]);
        }

        // causal mask + per-row max (rows live on 16-lane groups)
        float mx[4] = {-3e38f, -3e38f, -3e38f, -3e38f};
        #pragma unroll
        for (int nt = 0; nt < 4; ++nt)
            #pragma unroll
            for (int reg = 0; reg < 4; ++reg) {
                if (j0 + nt * 16 + l16 > irow + reg) s[nt][reg] = -3e38f;
                mx[reg] = fmaxf(mx[reg], s[nt][reg]);
            }
        #pragma unroll
        for (int off = 8; off; off >>= 1)
            #pragma unroll
            for (int reg = 0; reg < 4; ++reg)
                mx[reg] = fmaxf(mx[reg], __shfl_xor(mx[reg], off));

        float al[4];
        #pragma unroll
        for (int reg = 0; reg < 4; ++reg) {
            const float mn = fmaxf(mrow[reg], mx[reg]);
            al[reg] = __expf(mrow[reg] - mn);
            mrow[reg] = mn;
        }
        float rs[4] = {0.f, 0.f, 0.f, 0.f};
        #pragma unroll
        for (int nt = 0; nt < 4; ++nt)
            #pragma unroll
            for (int reg = 0; reg < 4; ++reg) {
                const float p = (j0 + nt * 16 + l16 > irow + reg)
                                    ? 0.f : __expf(s[nt][reg] - mrow[reg]);
                rs[reg] += p;
                ps[w][(quad * 4 + reg) * 72 + nt * 16 + l16] = (_Float16)p;
            }
        #pragma unroll
        for (int off = 8; off; off >>= 1)
            #pragma unroll
            for (int reg = 0; reg < 4; ++reg)
                rs[reg] += __shfl_xor(rs[reg], off);
        #pragma unroll
        for (int reg = 0; reg < 4; ++reg)
            lrow[reg] = lrow[reg] * al[reg] + rs[reg];
        #pragma unroll
        for (int nt = 0; nt < 4; ++nt)
            #pragma unroll
            for (int reg = 0; reg < 4; ++reg)
                o[nt][reg] *= al[reg];

        // PV: A = P (wave-private LDS, in-order per wave -> no barrier), B = V^T
        v8h Pa0 = *(const v8h*)(&ps[w][l16 * 72 + quad * 8]);
        v8h Pa1 = *(const v8h*)(&ps[w][l16 * 72 + 32 + quad * 8]);
        #pragma unroll
        for (int nt = 0; nt < 4; ++nt) {
            const size_t vrow = ((size_t)(b * HS + nt * 16 + l16)) * TT + j0;
            v8h Vb0 = *(const v8h*)(vt + vrow + quad * 8);
            v8h Vb1 = *(const v8h*)(vt + vrow + 32 + quad * 8);
            o[nt] = MFMA_F16(Pa0, Vb0, o[nt]);
            o[nt] = MFMA_F16(Pa1, Vb1, o[nt]);
        }
    }

    // merge the 8 key-split waves
    if (l16 == 0) {
        #pragma unroll
        for (int reg = 0; reg < 4; ++reg) {
            sm[w][quad * 4 + reg] = mrow[reg];
            sl[w][quad * 4 + reg] = lrow[reg];
        }
    }
    __syncthreads();
    float sc[4];
    #pragma unroll
    for (int reg = 0; reg < 4; ++reg) {
        const int r = quad * 4 + reg;
        float M = sm[0][r];
        #pragma unroll
        for (int i = 1; i < 8; ++i) M = fmaxf(M, sm[i][r]);
        sc[reg] = __expf(mrow[reg] - M);
    }
    #pragma unroll
    for (int nt = 0; nt < 4; ++nt)
        #pragma unroll
        for (int reg = 0; reg < 4; ++reg)
            os[w][(quad * 4 + reg) * 68 + nt * 16 + l16] = o[nt][reg] * sc[reg];
    __syncthreads();

    for (int m = w; m < 16; m += 8) {
        float M = sm[0][m];
        #pragma unroll
        for (int i = 1; i < 8; ++i) M = fmaxf(M, sm[i][m]);
        float L = 0.f, val = 0.f;
        #pragma unroll
        for (int i = 0; i < 8; ++i) {
            L   += sl[i][m] * __expf(sm[i][m] - M);
            val += os[i][m * 68 + lane];
        }
        out[((size_t)b * TT + q0 + m) * HS + lane] = val / L;
    }
}

// ---------------------------------------------------------------------------
extern "C" void kernel_launch(void* const* d_in, const int* in_sizes, int n_in,
                              void* d_out, int out_size, void* d_ws, size_t ws_size,
                              hipStream_t stream)
{
    const float* x  = (const float*)d_in[0];
    const float* Wq = (const float*)d_in[1];
    const float* bq = (const float*)d_in[2];
    const float* Wk = (const float*)d_in[3];
    const float* bk = (const float*)d_in[4];
    const float* Wv = (const float*)d_in[5];
    const float* bv = (const float*)d_in[6];
    float* out = (float*)d_out;

    const int rows = in_sizes[0] / NE;   // 8192
    char* p = (char*)d_ws;
    __bf16* wth = (__bf16*)p;                 p += (size_t)192 * NE * 2;
    __bf16* wtl = (__bf16*)p;                 p += (size_t)192 * NE * 2;
    __bf16* qhb = (__bf16*)p;                 p += (size_t)rows * HS * 2;
    __bf16* qlb = (__bf16*)p;                 p += (size_t)rows * HS * 2;
    __bf16* khb = (__bf16*)p;                 p += (size_t)rows * HS * 2;
    __bf16* klb = (__bf16*)p;                 p += (size_t)rows * HS * 2;
    _Float16* vtb = (_Float16*)p;             p += (size_t)rows * HS * 2;

    prep_w<<<dim3(16, 3), 256, 0, stream>>>(Wq, Wk, Wv, wth, wtl);
    proj<<<rows / 16, 256, 0, stream>>>(x, wth, wtl, bq, bk, bv,
                                        qhb, qlb, khb, klb, vtb);
    attn<<<rows / 16, 512, 0, stream>>>(qhb, qlb, khb, klb, vtb, out);
}

// Round 4
// 166.447 us; speedup vs baseline: 1.0890x; 1.0890x over previous
//
#include <hip/hip_runtime.h>
#include <math.h>

// B=4, T=2048, N_EMBD=1024, HEAD=64. Scores scaled by *sqrt(64)=8 (faithful).
#define NE 1024
#define HS 64
#define TT 2048

typedef __bf16    v8bf __attribute__((ext_vector_type(8)));
typedef _Float16  v8h  __attribute__((ext_vector_type(8)));
typedef float     v4f  __attribute__((ext_vector_type(4)));

#define MFMA_BF(a, b, c)  __builtin_amdgcn_mfma_f32_16x16x32_bf16((a), (b), (c), 0, 0, 0)
#define MFMA_F16(a, b, c) __builtin_amdgcn_mfma_f32_16x16x32_f16((a), (b), (c), 0, 0, 0)

// ---------------------------------------------------------------------------
// Prep: split Wq|Wk|Wv into transposed hi/lo bf16 wt[n][k] (n=0..191) via LDS
// transpose so both the W read and the wt writes are fully coalesced.
// ---------------------------------------------------------------------------
__global__ __launch_bounds__(256) void prep_w(
    const float* __restrict__ Wq, const float* __restrict__ Wk,
    const float* __restrict__ Wv, __bf16* __restrict__ wth, __bf16* __restrict__ wtl)
{
    __shared__ float t[64][65];
    const int k0 = blockIdx.x * 64, n0 = blockIdx.y * 64;
    const float* W = (n0 == 0) ? Wq : ((n0 == 64) ? Wk : Wv);
    const int tid = threadIdx.x;
    const int c = tid & 63, r4 = tid >> 6;
    #pragma unroll
    for (int p = 0; p < 16; ++p) {
        const int k = p * 4 + r4;
        t[k][c] = W[(size_t)(k0 + k) * HS + c];
    }
    __syncthreads();
    #pragma unroll
    for (int p = 0; p < 16; ++p) {
        const int n = p * 4 + r4;
        const float w = t[c][n];
        const __bf16 h = (__bf16)w;
        const size_t o = (size_t)(n0 + n) * NE + k0 + c;
        wth[o] = h;
        wtl[o] = (__bf16)(w - (float)h);
    }
}

// ---------------------------------------------------------------------------
// Projection GEMM, split-precision bf16 MFMA, m97-style pipelined K-loop.
// Grid: (128 m-blocks, 4 n-blocks). Block tile 64m x 48n, 4 waves; wave w
// owns rows w*16..w*16+15, all 48 cols (3 n-tiles, 9 MFMA per k-step).
// x staged fp32 in LDS (padded stride 36 -> every LDS op 2-way aliased = free)
// with register prefetch one k-step ahead; W hi/lo fragments prefetched one
// k-step ahead in registers (L2-hot: same 768 KB for all m-blocks).
// ---------------------------------------------------------------------------
__global__ __launch_bounds__(256) void proj(
    const float* __restrict__ x, const __bf16* __restrict__ wth,
    const __bf16* __restrict__ wtl,
    const float* __restrict__ bq, const float* __restrict__ bk,
    const float* __restrict__ bv,
    __bf16* __restrict__ qh, __bf16* __restrict__ ql,
    __bf16* __restrict__ kh, __bf16* __restrict__ kl,
    _Float16* __restrict__ vt)
{
    __shared__ __align__(16) float xs[64 * 36];   // 9.2 KB, stride 36 floats

    const int m0 = blockIdx.x * 64;
    const int n0 = blockIdx.y * 48;
    const int tid = threadIdx.x, lane = tid & 63, w = tid >> 6;
    const int quad = lane >> 4, l16 = lane & 15;
    const int sr = tid >> 3, sc = tid & 7;        // staging: 2 float4/thread

    v4f acc[3];
    #pragma unroll
    for (int i = 0; i < 3; ++i) acc[i] = (v4f){0.f, 0.f, 0.f, 0.f};

    const float* xp0 = x + (size_t)(m0 + sr) * NE + sc * 4;
    const float* xp1 = x + (size_t)(m0 + sr + 32) * NE + sc * 4;
    const __bf16* bhp = wth + (size_t)(n0 + l16) * NE + quad * 8;
    const __bf16* blp = wtl + (size_t)(n0 + l16) * NE + quad * 8;

    // prologue: prefetch tile 0
    float4 xa = *(const float4*)(xp0);
    float4 xb = *(const float4*)(xp1);
    v8bf bh[3], bl[3];
    #pragma unroll
    for (int j = 0; j < 3; ++j) {
        bh[j] = *(const v8bf*)(bhp + (size_t)j * 16 * NE);
        bl[j] = *(const v8bf*)(blp + (size_t)j * 16 * NE);
    }

    for (int k0 = 0; k0 < NE; k0 += 32) {
        // stage current x tile (regs -> LDS)
        *(float4*)(xs + sr * 36 + sc * 4)        = xa;
        *(float4*)(xs + (sr + 32) * 36 + sc * 4) = xb;
        // grab current W frags, then issue next-step prefetches
        v8bf cbh0 = bh[0], cbh1 = bh[1], cbh2 = bh[2];
        v8bf cbl0 = bl[0], cbl1 = bl[1], cbl2 = bl[2];
        if (k0 + 32 < NE) {
            xa = *(const float4*)(xp0 + k0 + 32);
            xb = *(const float4*)(xp1 + k0 + 32);
            #pragma unroll
            for (int j = 0; j < 3; ++j) {
                bh[j] = *(const v8bf*)(bhp + (size_t)j * 16 * NE + k0 + 32);
                bl[j] = *(const v8bf*)(blp + (size_t)j * 16 * NE + k0 + 32);
            }
        }
        __syncthreads();

        // A fragment from LDS, convert to hi/lo bf16 in registers
        const float* arow = xs + (w * 16 + l16) * 36 + quad * 8;
        const float4 a0 = *(const float4*)(arow);
        const float4 a1 = *(const float4*)(arow + 4);
        const float av[8] = {a0.x, a0.y, a0.z, a0.w, a1.x, a1.y, a1.z, a1.w};
        v8bf ah, al;
        #pragma unroll
        for (int i = 0; i < 8; ++i) {
            const __bf16 h = (__bf16)av[i];
            ah[i] = h;
            al[i] = (__bf16)(av[i] - (float)h);
        }
        acc[0] = MFMA_BF(ah, cbh0, acc[0]);
        acc[1] = MFMA_BF(ah, cbh1, acc[1]);
        acc[2] = MFMA_BF(ah, cbh2, acc[2]);
        acc[0] = MFMA_BF(ah, cbl0, acc[0]);
        acc[1] = MFMA_BF(ah, cbl1, acc[1]);
        acc[2] = MFMA_BF(ah, cbl2, acc[2]);
        acc[0] = MFMA_BF(al, cbh0, acc[0]);
        acc[1] = MFMA_BF(al, cbh1, acc[1]);
        acc[2] = MFMA_BF(al, cbh2, acc[2]);
        __syncthreads();
    }

    // epilogue: C layout col=l16 (within n-tile), row=quad*4+reg
    #pragma unroll
    for (int j = 0; j < 3; ++j) {
        const int n = n0 + j * 16 + l16;
        const float bias = (n < 64) ? bq[n] : ((n < 128) ? bk[n - 64] : bv[n - 128]);
        #pragma unroll
        for (int reg = 0; reg < 4; ++reg) {
            const int row = m0 + w * 16 + quad * 4 + reg;
            const float v = acc[j][reg] + bias;
            if (n < 64) {
                const float s = v * 8.0f;            // fold score scale into q
                const __bf16 h = (__bf16)s;
                qh[(size_t)row * HS + n] = h;
                ql[(size_t)row * HS + n] = (__bf16)(s - (float)h);
            } else if (n < 128) {
                const __bf16 h = (__bf16)v;
                kh[(size_t)row * HS + n - 64] = h;
                kl[(size_t)row * HS + n - 64] = (__bf16)(v - (float)h);
            } else {
                const int b = row >> 11, tt = row & 2047, hc = n - 128;
                vt[((size_t)(b * HS + hc)) * TT + tt] = (_Float16)v;
            }
        }
    }
}

// ---------------------------------------------------------------------------
// Flash attention, MFMA. Block = 16 q-rows, 4 waves split the key range
// (round-robin 64-key tiles), independent online softmax, merged at the end.
// ALL 24 fragment loads (K hi/lo + V) batched at iteration top: one latency
// wall per tile; V arrives under QK+softmax. P via wave-private LDS (fp16).
// LDS union: P-buffer and O-merge buffer share storage (~18 KB).
// ---------------------------------------------------------------------------
__global__ __launch_bounds__(256) void attn(
    const __bf16* __restrict__ qh, const __bf16* __restrict__ ql,
    const __bf16* __restrict__ kh, const __bf16* __restrict__ kl,
    const _Float16* __restrict__ vt, float* __restrict__ out)
{
    __shared__ __align__(16) char smem_raw[4 * 16 * 68 * 4];  // 17408 B
    _Float16* ps = (_Float16*)smem_raw;   // [w][16*72] fp16 (k-loop only)
    float*    os = (float*)smem_raw;      // [w][16*68] fp32 (merge only)
    __shared__ float sm[4][16], sl[4][16];

    const int tid = threadIdx.x, lane = tid & 63, w = tid >> 6;
    const int quad = lane >> 4, l16 = lane & 15;
    const int b = blockIdx.x & 3, qi = blockIdx.x >> 2;
    const int q0 = (127 - qi) * 16;                 // heavy tiles first

    const size_t qrow = ((size_t)b * TT + q0 + l16) * HS;
    const v8bf Qh0 = *(const v8bf*)(qh + qrow + quad * 8);
    const v8bf Qh1 = *(const v8bf*)(qh + qrow + 32 + quad * 8);
    const v8bf Ql0 = *(const v8bf*)(ql + qrow + quad * 8);
    const v8bf Ql1 = *(const v8bf*)(ql + qrow + 32 + quad * 8);

    float mrow[4] = {-3e38f, -3e38f, -3e38f, -3e38f};
    float lrow[4] = {0.f, 0.f, 0.f, 0.f};
    v4f o[4];
    #pragma unroll
    for (int i = 0; i < 4; ++i) o[i] = (v4f){0.f, 0.f, 0.f, 0.f};

    const int irow = q0 + quad * 4;                 // + reg
    const int ntk = (q0 + 16 + 63) >> 6;
    _Float16* pw = ps + w * (16 * 72);

    for (int t = w; t < ntk; t += 4) {
        const int j0 = t * 64;

        // ---- batched fragment loads: 16 K + 8 V, one vmcnt wall ----
        v8bf Kh[8], Kl[8];
        v8h  Vf[8];
        #pragma unroll
        for (int nt = 0; nt < 4; ++nt) {
            const size_t krow = ((size_t)b * TT + j0 + nt * 16 + l16) * HS;
            Kh[nt * 2]     = *(const v8bf*)(kh + krow + quad * 8);
            Kh[nt * 2 + 1] = *(const v8bf*)(kh + krow + 32 + quad * 8);
            Kl[nt * 2]     = *(const v8bf*)(kl + krow + quad * 8);
            Kl[nt * 2 + 1] = *(const v8bf*)(kl + krow + 32 + quad * 8);
        }
        #pragma unroll
        for (int nt = 0; nt < 4; ++nt) {
            const size_t vrow = ((size_t)(b * HS + nt * 16 + l16)) * TT + j0;
            Vf[nt * 2]     = *(const v8h*)(vt + vrow + quad * 8);
            Vf[nt * 2 + 1] = *(const v8h*)(vt + vrow + 32 + quad * 8);
        }

        v4f s[4];
        #pragma unroll
        for (int i = 0; i < 4; ++i) s[i] = (v4f){0.f, 0.f, 0.f, 0.f};
        #pragma unroll
        for (int nt = 0; nt < 4; ++nt) {
            s[nt] = MFMA_BF(Qh0, Kh[nt * 2],     s[nt]);
            s[nt] = MFMA_BF(Qh1, Kh[nt * 2 + 1], s[nt]);
            s[nt] = MFMA_BF(Qh0, Kl[nt * 2],     s[nt]);
            s[nt] = MFMA_BF(Qh1, Kl[nt * 2 + 1], s[nt]);
            s[nt] = MFMA_BF(Ql0, Kh[nt * 2],     s[nt]);
            s[nt] = MFMA_BF(Ql1, Kh[nt * 2 + 1], s[nt]);
        }

        // causal mask + per-row max (rows live on 16-lane groups)
        float mx[4] = {-3e38f, -3e38f, -3e38f, -3e38f};
        #pragma unroll
        for (int nt = 0; nt < 4; ++nt)
            #pragma unroll
            for (int reg = 0; reg < 4; ++reg) {
                if (j0 + nt * 16 + l16 > irow + reg) s[nt][reg] = -3e38f;
                mx[reg] = fmaxf(mx[reg], s[nt][reg]);
            }
        #pragma unroll
        for (int off = 8; off; off >>= 1)
            #pragma unroll
            for (int reg = 0; reg < 4; ++reg)
                mx[reg] = fmaxf(mx[reg], __shfl_xor(mx[reg], off));

        float al[4];
        #pragma unroll
        for (int reg = 0; reg < 4; ++reg) {
            const float mn = fmaxf(mrow[reg], mx[reg]);
            al[reg] = __expf(mrow[reg] - mn);
            mrow[reg] = mn;
        }
        float rs[4] = {0.f, 0.f, 0.f, 0.f};
        #pragma unroll
        for (int nt = 0; nt < 4; ++nt)
            #pragma unroll
            for (int reg = 0; reg < 4; ++reg) {
                const float p = (j0 + nt * 16 + l16 > irow + reg)
                                    ? 0.f : __expf(s[nt][reg] - mrow[reg]);
                rs[reg] += p;
                pw[(quad * 4 + reg) * 72 + nt * 16 + l16] = (_Float16)p;
            }
        #pragma unroll
        for (int off = 8; off; off >>= 1)
            #pragma unroll
            for (int reg = 0; reg < 4; ++reg)
                rs[reg] += __shfl_xor(rs[reg], off);
        #pragma unroll
        for (int reg = 0; reg < 4; ++reg)
            lrow[reg] = lrow[reg] * al[reg] + rs[reg];
        #pragma unroll
        for (int nt = 0; nt < 4; ++nt)
            #pragma unroll
            for (int reg = 0; reg < 4; ++reg)
                o[nt][reg] *= al[reg];

        // PV: A = P (wave-private LDS, in-order per wave), B = V (prefetched)
        v8h Pa0 = *(const v8h*)(pw + l16 * 72 + quad * 8);
        v8h Pa1 = *(const v8h*)(pw + l16 * 72 + 32 + quad * 8);
        #pragma unroll
        for (int nt = 0; nt < 4; ++nt) {
            o[nt] = MFMA_F16(Pa0, Vf[nt * 2],     o[nt]);
            o[nt] = MFMA_F16(Pa1, Vf[nt * 2 + 1], o[nt]);
        }
    }

    // merge the 4 key-split waves
    if (l16 == 0) {
        #pragma unroll
        for (int reg = 0; reg < 4; ++reg) {
            sm[w][quad * 4 + reg] = mrow[reg];
            sl[w][quad * 4 + reg] = lrow[reg];
        }
    }
    __syncthreads();   // also fences last ps reads before os overwrite
    float sc[4];
    #pragma unroll
    for (int reg = 0; reg < 4; ++reg) {
        const int r = quad * 4 + reg;
        float M = sm[0][r];
        #pragma unroll
        for (int i = 1; i < 4; ++i) M = fmaxf(M, sm[i][r]);
        sc[reg] = __expf(mrow[reg] - M);
    }
    float* ow = os + w * (16 * 68);
    #pragma unroll
    for (int nt = 0; nt < 4; ++nt)
        #pragma unroll
        for (int reg = 0; reg < 4; ++reg)
            ow[(quad * 4 + reg) * 68 + nt * 16 + l16] = o[nt][reg] * sc[reg];
    __syncthreads();

    #pragma unroll
    for (int kk = 0; kk < 4; ++kk) {
        const int m = w * 4 + kk;
        float M = sm[0][m];
        #pragma unroll
        for (int i = 1; i < 4; ++i) M = fmaxf(M, sm[i][m]);
        float L = 0.f, val = 0.f;
        #pragma unroll
        for (int i = 0; i < 4; ++i) {
            L   += sl[i][m] * __expf(sm[i][m] - M);
            val += os[i * (16 * 68) + m * 68 + lane];
        }
        out[((size_t)b * TT + q0 + m) * HS + lane] = val / L;
    }
}

// ---------------------------------------------------------------------------
extern "C" void kernel_launch(void* const* d_in, const int* in_sizes, int n_in,
                              void* d_out, int out_size, void* d_ws, size_t ws_size,
                              hipStream_t stream)
{
    const float* x  = (const float*)d_in[0];
    const float* Wq = (const float*)d_in[1];
    const float* bq = (const float*)d_in[2];
    const float* Wk = (const float*)d_in[3];
    const float* bk = (const float*)d_in[4];
    const float* Wv = (const float*)d_in[5];
    const float* bv = (const float*)d_in[6];
    float* out = (float*)d_out;

    const int rows = in_sizes[0] / NE;   // 8192
    char* p = (char*)d_ws;
    __bf16* wth = (__bf16*)p;                 p += (size_t)192 * NE * 2;
    __bf16* wtl = (__bf16*)p;                 p += (size_t)192 * NE * 2;
    __bf16* qhb = (__bf16*)p;                 p += (size_t)rows * HS * 2;
    __bf16* qlb = (__bf16*)p;                 p += (size_t)rows * HS * 2;
    __bf16* khb = (__bf16*)p;                 p += (size_t)rows * HS * 2;
    __bf16* klb = (__bf16*)p;                 p += (size_t)rows * HS * 2;
    _Float16* vtb = (_Float16*)p;             p += (size_t)rows * HS * 2;

    prep_w<<<dim3(16, 3), 256, 0, stream>>>(Wq, Wk, Wv, wth, wtl);
    proj<<<dim3(rows / 64, 4), 256, 0, stream>>>(x, wth, wtl, bq, bk, bv,
                                                 qhb, qlb, khb, klb, vtb);
    attn<<<rows / 16, 256, 0, stream>>>(qhb, qlb, khb, klb, vtb, out);
}